// Round 18
// baseline (1528.320 us; speedup 1.0000x reference)
//
#include <hip/hip_runtime.h>
#include <hip/hip_fp16.h>

#define NN 262144
#define EE 1048576
#define GG 8192
#define HH 128
#define FBc 3
#define VAc 64
#define VBc 8
#define FAc 9

typedef _Float16 f16;
typedef _Float16 f16x8 __attribute__((ext_vector_type(8)));
typedef float f32x4 __attribute__((ext_vector_type(4)));

__device__ __forceinline__ float h2f(ushort u) {
    __half h; *(ushort*)&h = u; return __half2float(h);
}
__device__ __forceinline__ ushort f2h(float f) {
    __half h = __float2half_rn(f); return *(ushort*)&h;
}
__device__ __forceinline__ int swz(int col, int row) {
    return (((col >> 3) ^ (row & 7)) << 3) | (col & 7);
}

// ---------------- zero fill ----------------
__global__ void k_zero(float* __restrict__ p) {
    size_t i = (size_t)(blockIdx.x * 256 + threadIdx.x) * 4;
    *(float4*)(p + i) = make_float4(0.f, 0.f, 0.f, 0.f);
}

// ---------------- atom encoder: h16 = (sum emb)/16 fp16 ----------------
__global__ void k_atom(const int* __restrict__ x, const float* __restrict__ emb,
                       ushort* __restrict__ h16) {
    int t = blockIdx.x * 256 + threadIdx.x;
    int n = t >> 5, c = (t & 31) << 2;
    if (n >= NN) return;
    float4 a = make_float4(0.f, 0.f, 0.f, 0.f);
#pragma unroll
    for (int f = 0; f < FAc; ++f) {
        int v = x[n * FAc + f];
        float4 e = *(const float4*)(emb + ((size_t)(f * VAc + v)) * HH + c);
        a.x += e.x; a.y += e.y; a.z += e.z; a.w += e.w;
    }
    ushort4 o;
    o.x = f2h(a.x * 0.0625f); o.y = f2h(a.y * 0.0625f);
    o.z = f2h(a.z * 0.0625f); o.w = f2h(a.w * 0.0625f);
    *(ushort4*)(h16 + (size_t)n * HH + c) = o;
}

// ---------------- vn init ----------------
__global__ void k_init_vn(const float* __restrict__ vn_emb, float* __restrict__ vn) {
    int t = blockIdx.x * 256 + threadIdx.x;
    int g = t >> 5, c = (t & 31) << 2;
    *(float4*)(vn + (size_t)g * HH + c) = *(const float4*)(vn_emb + c);
}

// ---------------- hb16 = h16 + vn[batch]/16, plus pooled zero (tail blocks) ----------------
__global__ void k_hb16(const ushort* __restrict__ h16, const float* __restrict__ vn,
                       const int* __restrict__ batch, ushort* __restrict__ hb16,
                       float* __restrict__ pooled) {
    int b = blockIdx.x;
    if (b >= NN * 16 / 256) {               // tail: zero pooled
        size_t i = (size_t)((b - NN * 16 / 256) * 256 + threadIdx.x) * 4;
        *(float4*)(pooled + i) = make_float4(0.f, 0.f, 0.f, 0.f);
        return;
    }
    int t = b * 256 + threadIdx.x;          // NN*16 threads
    int n = t >> 4, ch0 = (t & 15) * 8;
    int g = batch[n];
    f16x8 hv = *(const f16x8*)(h16 + (size_t)n * HH + ch0);
    const float* vp = vn + (size_t)g * HH + ch0;
    float4 v0 = *(const float4*)vp, v1 = *(const float4*)(vp + 4);
    float vv[8] = {v0.x, v0.y, v0.z, v0.w, v1.x, v1.y, v1.z, v1.w};
    f16x8 o;
#pragma unroll
    for (int j = 0; j < 8; ++j) o[j] = (f16)((float)hv[j] + vv[j] * 0.0625f);
    *(f16x8*)(hb16 + (size_t)n * HH + ch0) = o;
}

// ================= CSR build =================
__global__ void k_hist(const int* __restrict__ ei, int* __restrict__ deg) {
    int e = blockIdx.x * 256 + threadIdx.x;
    atomicAdd(&deg[ei[EE + e]], 1);
}
__global__ void k_scan1(const int* __restrict__ deg, int* __restrict__ rowptr,
                        int* __restrict__ sums) {
    __shared__ int s[256];
    int base = blockIdx.x * 1024 + threadIdx.x * 4;
    int4 d = *(const int4*)(deg + base);
    int t = d.x + d.y + d.z + d.w;
    s[threadIdx.x] = t;
    __syncthreads();
    for (int off = 1; off < 256; off <<= 1) {
        int v = (threadIdx.x >= off) ? s[threadIdx.x - off] : 0;
        __syncthreads();
        s[threadIdx.x] += v;
        __syncthreads();
    }
    int excl = s[threadIdx.x] - t;
    int4 o; o.x = excl; o.y = excl + d.x; o.z = o.y + d.y; o.w = o.z + d.z;
    *(int4*)(rowptr + base) = o;
    if (threadIdx.x == 255) sums[blockIdx.x] = s[255];
}
__global__ void k_scan2(int* __restrict__ sums) {
    __shared__ int s[256];
    int t = sums[threadIdx.x];
    s[threadIdx.x] = t;
    __syncthreads();
    for (int off = 1; off < 256; off <<= 1) {
        int v = (threadIdx.x >= off) ? s[threadIdx.x - off] : 0;
        __syncthreads();
        s[threadIdx.x] += v;
        __syncthreads();
    }
    sums[threadIdx.x] = s[threadIdx.x] - t;
}
__global__ void k_scan3(int* __restrict__ rowptr, const int* __restrict__ sums,
                        int* __restrict__ fill) {
    int base = blockIdx.x * 1024 + threadIdx.x * 4;
    int add = sums[blockIdx.x];
    int4 r = *(const int4*)(rowptr + base);
    r.x += add; r.y += add; r.z += add; r.w += add;
    *(int4*)(rowptr + base) = r;
    *(int4*)(fill + base) = r;
    if (blockIdx.x == 0 && threadIdx.x == 0) rowptr[NN] = EE;
}
__global__ void k_scatter(const int* __restrict__ ei, const int* __restrict__ ea,
                          int* __restrict__ fill, unsigned* __restrict__ packed) {
    int e = blockIdx.x * 256 + threadIdx.x;
    int dst = ei[EE + e];
    int pos = atomicAdd(&fill[dst], 1);
    unsigned cb = (unsigned)(ea[e * 3 + 0] + ea[e * 3 + 1] * 8 + ea[e * 3 + 2] * 64);
    packed[pos] = (unsigned)ei[e] | (cb << 18);
}

// ============ one-shot setup for ALL layers ============
__global__ void k_setup_all(
    const float* __restrict__ bond_emb, ushort* __restrict__ ct16_all,
    const float* __restrict__ conv_b1, const float* __restrict__ cbn_g,
    const float* __restrict__ cbn_b, const float* __restrict__ cbn_m,
    const float* __restrict__ cbn_v,
    const float* __restrict__ vn1_g, const float* __restrict__ vn1_be,
    const float* __restrict__ vn1_m, const float* __restrict__ vn1_v,
    float* __restrict__ tabs,                      // per layer 1280 floats: ZA ZB TA TB S3
    const float* __restrict__ conv_W1, ushort* __restrict__ W1t_all,
    const float* __restrict__ conv_W2, ushort* __restrict__ W2t_all,
    const float* __restrict__ vn1_W,  ushort* __restrict__ W3t_all) {
    int layer = blockIdx.x / 449;
    int t = (blockIdx.x % 449) * 256 + threadIdx.x;
    if (t < 16384) {                        // ct16: (sum bemb)/16
        const float* bemb = bond_emb + (size_t)layer * FBc * VBc * HH;
        int cb = t >> 5, c = (t & 31) << 2;
        int a0 = cb & 7, a1 = (cb >> 3) & 7, a2 = cb >> 6;
        float4 b0 = *(const float4*)(bemb + (size_t)(0 * VBc + a0) * HH + c);
        float4 b1v = *(const float4*)(bemb + (size_t)(1 * VBc + a1) * HH + c);
        float4 b2v = *(const float4*)(bemb + (size_t)(2 * VBc + a2) * HH + c);
        ushort4 o;
        o.x = f2h((b0.x + b1v.x + b2v.x) * 0.0625f);
        o.y = f2h((b0.y + b1v.y + b2v.y) * 0.0625f);
        o.z = f2h((b0.z + b1v.z + b2v.z) * 0.0625f);
        o.w = f2h((b0.w + b1v.w + b2v.w) * 0.0625f);
        *(ushort4*)(ct16_all + (size_t)layer * 512 * HH + (size_t)cb * HH + c) = o;
    } else if (t < 16640) {                 // BN tables
        int c = t - 16384;
        float* T = tabs + (size_t)layer * 1280;
        float s1 = cbn_g[layer * 256 + c] * rsqrtf(cbn_v[layer * 256 + c] + 1e-5f);
        T[0 * 256 + c] = s1;
        T[1 * 256 + c] = ((conv_b1[layer * 256 + c] - cbn_m[layer * 256 + c]) * s1
                          + cbn_b[layer * 256 + c]) * 0.0625f;
        float s3 = vn1_g[layer * 256 + c] * rsqrtf(vn1_v[layer * 256 + c] + 1e-5f);
        T[2 * 256 + c] = 16.f * s3;
        T[3 * 256 + c] = vn1_be[layer * 256 + c] - vn1_m[layer * 256 + c] * s3;
        T[4 * 256 + c] = s3;
    } else if (t < 49408) {                 // W1t [256][128]
        int o = t - 16640;
        int c = o >> 7, k = o & 127;
        W1t_all[(size_t)layer * 32768 + o] =
            f2h(conv_W1[(size_t)layer * 128 * 256 + (size_t)k * 256 + c]);
    } else if (t < 82176) {                 // W2t [128][256]
        int o = t - 49408;
        int c = o >> 8, k = o & 255;
        W2t_all[(size_t)layer * 32768 + o] =
            f2h(conv_W2[(size_t)layer * 256 * 128 + (size_t)k * 128 + c]);
    } else if (t < 114944) {                // W3t [256][128]
        int o = t - 82176;
        int c = o >> 7, k = o & 127;
        W3t_all[(size_t)layer * 32768 + o] =
            f2h(vn1_W[(size_t)layer * 256 * 256 + 128 * 256 + (size_t)k * 256 + c]);
    }
}

// ============== mega-kernel v8: interleaved-row edge gather + conv MLP + pool ==============
__global__ void __launch_bounds__(256, 3)
k_conv(ushort* __restrict__ h16, const ushort* __restrict__ hb16,
       const int* __restrict__ rowptr, const unsigned* __restrict__ packed,
       const ushort* __restrict__ ct16,
       const ushort* __restrict__ W1t, const ushort* __restrict__ W2t,
       const ushort* __restrict__ W3t,
       const int* __restrict__ batch, const float* __restrict__ vnW,
       const float* __restrict__ eps_ptr, const float* __restrict__ tabs,
       const float* __restrict__ b2,
       float* __restrict__ pooled) {
    __shared__ ushort zs[64][256];
    __shared__ ushort Wb[64][128];
    ushort(*Wb2)[256] = (ushort(*)[256]) & Wb[0][0];
    const int tid = threadIdx.x;
    const int r0 = blockIdx.x * 64;
    const int w = tid >> 6, l = tid & 63, lr = l & 15, lg = l >> 4, lr7 = lr & 7;
    const float eps1 = 1.f + eps_ptr[0];
    const int myrow = w * 16 + lr;
    const int growA = r0 + myrow;
    const float* ZA = tabs;
    const float* ZB = tabs + 256;
    const float* TA = tabs + 512;
    const float* TB = tabs + 768;
    int rl[4], ggs[4];
#pragma unroll
    for (int reg = 0; reg < 4; ++reg) {
        rl[reg] = w * 16 + lg * 4 + reg;
        ggs[reg] = batch[r0 + rl[reg]];
    }

    // ---- fused edge gather, 4 rows INTERLEAVED (16 loads in flight) ----
    {
        int grp = tid >> 4, ln = tid & 15;
        int ch0 = ln * 8;
        int ep[4], ee[4];
        float ac[4][8];
#pragma unroll
        for (int rr = 0; rr < 4; ++rr) {
            int row = grp * 4 + rr;
            ep[rr] = rowptr[r0 + row];
            ee[rr] = rowptr[r0 + row + 1];
#pragma unroll
            for (int j = 0; j < 8; ++j) ac[rr][j] = 0.f;
        }
        bool more = (ep[0] < ee[0]) | (ep[1] < ee[1]) | (ep[2] < ee[2]) | (ep[3] < ee[3]);
        while (more) {
            f16x8 hv0[4], hv1[4], ct0[4], ct1[4];
            int cnt[4];
#pragma unroll
            for (int rr = 0; rr < 4; ++rr) {
                int rem = ee[rr] - ep[rr];
                cnt[rr] = rem < 2 ? rem : 2;
                if (cnt[rr] > 0) {
                    unsigned p = packed[ep[rr]];
                    hv0[rr] = *(const f16x8*)(hb16 + (size_t)(p & 0x3FFFF) * HH + ch0);
                    ct0[rr] = *(const f16x8*)(ct16 + (size_t)(p >> 18) * HH + ch0);
                }
                if (cnt[rr] > 1) {
                    unsigned p = packed[ep[rr] + 1];
                    hv1[rr] = *(const f16x8*)(hb16 + (size_t)(p & 0x3FFFF) * HH + ch0);
                    ct1[rr] = *(const f16x8*)(ct16 + (size_t)(p >> 18) * HH + ch0);
                }
            }
#pragma unroll
            for (int rr = 0; rr < 4; ++rr) {
                if (cnt[rr] > 0) {
#pragma unroll
                    for (int j = 0; j < 8; ++j)
                        ac[rr][j] += fmaxf((float)hv0[rr][j] + (float)ct0[rr][j], 0.f);
                }
                if (cnt[rr] > 1) {
#pragma unroll
                    for (int j = 0; j < 8; ++j)
                        ac[rr][j] += fmaxf((float)hv1[rr][j] + (float)ct1[rr][j], 0.f);
                }
                ep[rr] += cnt[rr];
            }
            more = (ep[0] < ee[0]) | (ep[1] < ee[1]) | (ep[2] < ee[2]) | (ep[3] < ee[3]);
        }
#pragma unroll
        for (int rr = 0; rr < 4; ++rr) {
            int row = grp * 4 + rr;
            f16x8 o;
#pragma unroll
            for (int j = 0; j < 8; ++j) o[j] = (f16)ac[rr][j];
            *(f16x8*)&zs[row][((ch0 >> 3) ^ (row & 7)) << 3] = o;
        }
    }
    __syncthreads();

    // ---- A fragments: A/16 = eps1*hb16 + agg16(zs) ----
    f16x8 af[4];
#pragma unroll
    for (int k0 = 0; k0 < 4; ++k0) {
        int ko = k0 * 32 + lg * 8;
        f16x8 hb = *(const f16x8*)(hb16 + (size_t)growA * HH + ko);
        f16x8 ag = *(const f16x8*)&zs[myrow][((ko >> 3) ^ (myrow & 7)) << 3];
#pragma unroll
        for (int j = 0; j < 8; ++j)
            af[k0][j] = (f16)(eps1 * (float)hb[j] + (float)ag[j]);
    }

    // ---- phase A ----
    for (int qt = 0; qt < 4; ++qt) {
        __syncthreads();
        {
            int c = tid >> 2, q = tid & 3, c7 = c & 7;
            const ushort* s = W1t + (size_t)(qt * 64 + c) * 128 + q * 32;
#pragma unroll
            for (int j4 = 0; j4 < 4; ++j4)
                *(f16x8*)&Wb[c][((q * 4 + j4) ^ c7) << 3] = *(const f16x8*)(s + j4 * 8);
        }
        __syncthreads();
        f32x4 acc[4] = {};
        __builtin_amdgcn_s_setprio(1);
#pragma unroll
        for (int k0 = 0; k0 < 4; ++k0) {
            int sb = ((k0 * 4 + lg) ^ lr7) << 3;
#pragma unroll
            for (int fc = 0; fc < 4; ++fc) {
                f16x8 bf = *(const f16x8*)&Wb[fc * 16 + lr][sb];
                acc[fc] = __builtin_amdgcn_mfma_f32_16x16x32_f16(af[k0], bf, acc[fc], 0, 0, 0);
            }
        }
        __builtin_amdgcn_s_setprio(0);
#pragma unroll
        for (int fc = 0; fc < 4; ++fc) {
            int col = qt * 64 + fc * 16 + lr;
            float za = ZA[col], zb = ZB[col];
#pragma unroll
            for (int reg = 0; reg < 4; ++reg) {
                float zv = fmaxf(acc[fc][reg] * za + zb, 0.f);
                zs[rl[reg]][swz(col, rl[reg])] = f2h(zv);
            }
        }
    }

    // ---- phase B ----
    f32x4 acc2[8] = {};
    for (int st = 0; st < 4; ++st) {
        __syncthreads();
        {
            int c = tid >> 3, q = tid & 7, c7 = c & 7;
            const ushort* s = W2t + (size_t)(st * 32 + c) * 256 + q * 32;
#pragma unroll
            for (int j4 = 0; j4 < 4; ++j4)
                *(f16x8*)&Wb2[c][((q * 4 + j4) ^ c7) << 3] = *(const f16x8*)(s + j4 * 8);
        }
        __syncthreads();
        __builtin_amdgcn_s_setprio(1);
#pragma unroll
        for (int k0 = 0; k0 < 8; ++k0) {
            int sb = ((k0 * 4 + lg) ^ lr7) << 3;
            f16x8 az = *(const f16x8*)&zs[myrow][sb];
#pragma unroll
            for (int fc = 0; fc < 2; ++fc) {
                f16x8 bf = *(const f16x8*)&Wb2[fc * 16 + lr][sb];
                acc2[st * 2 + fc] =
                    __builtin_amdgcn_mfma_f32_16x16x32_f16(az, bf, acc2[st * 2 + fc], 0, 0, 0);
            }
        }
        __builtin_amdgcn_s_setprio(0);
    }
    __syncthreads();
#pragma unroll
    for (int st = 0; st < 4; ++st) {
#pragma unroll
        for (int fc = 0; fc < 2; ++fc) {
            int col = st * 32 + fc * 16 + lr;
            float bb = b2[col];
#pragma unroll
            for (int reg = 0; reg < 4; ++reg) {
                float hv = acc2[st * 2 + fc][reg] * 16.f + bb;
                zs[rl[reg]][swz(col, rl[reg])] = f2h(hv * 0.0625f);
            }
        }
    }
    {
        int row = tid >> 2, q = tid & 3, r7 = row & 7;
#pragma unroll
        for (int j4 = 0; j4 < 4; ++j4) {
            f16x8 v = *(const f16x8*)&zs[row][((q * 4 + j4) ^ r7) << 3];
            *(f16x8*)(h16 + (size_t)(r0 + row) * HH + q * 32 + j4 * 8) = v;
        }
    }

    // ---- phase C + pool ----
    for (int pr = 0; pr < 2; ++pr) {
#pragma unroll
        for (int sub = 0; sub < 2; ++sub) {
            int qt = pr * 2 + sub;
            __syncthreads();
            {
                int c = tid >> 2, q = tid & 3, c7 = c & 7;
                const ushort* s = W3t + (size_t)(qt * 64 + c) * 128 + q * 32;
#pragma unroll
                for (int j4 = 0; j4 < 4; ++j4)
                    *(f16x8*)&Wb[c][((q * 4 + j4) ^ c7) << 3] = *(const f16x8*)(s + j4 * 8);
            }
            __syncthreads();
            f32x4 acc3[4] = {};
            __builtin_amdgcn_s_setprio(1);
#pragma unroll
            for (int k0 = 0; k0 < 4; ++k0) {
                int sb = ((k0 * 4 + lg) ^ lr7) << 3;
                f16x8 ah = *(const f16x8*)&zs[myrow][sb];
#pragma unroll
                for (int fc = 0; fc < 4; ++fc) {
                    f16x8 bf = *(const f16x8*)&Wb[fc * 16 + lr][sb];
                    acc3[fc] = __builtin_amdgcn_mfma_f32_16x16x32_f16(ah, bf, acc3[fc], 0, 0, 0);
                }
            }
            __builtin_amdgcn_s_setprio(0);
#pragma unroll
            for (int fc = 0; fc < 4; ++fc) {
                int colg = qt * 64 + fc * 16 + lr;
                int colL = 128 + sub * 64 + fc * 16 + lr;
                float ta = TA[colg], tb = TB[colg];
#pragma unroll
                for (int reg = 0; reg < 4; ++reg) {
                    float tv = fmaxf(acc3[fc][reg] * ta + vnW[(size_t)ggs[reg] * 256 + colg] + tb, 0.f);
                    zs[rl[reg]][swz(colL, rl[reg])] = f2h(tv);
                }
            }
        }
        __syncthreads();
        {
            int c = tid & 127, half = tid >> 7;
            int gcol = pr * 128 + c;
            int colL = 128 + c;
            float s = 0.f;
            int cur = batch[r0 + half * 32];
            for (int r = half * 32; r < half * 32 + 32; ++r) {
                int gg = batch[r0 + r];
                if (gg != cur) {
                    atomicAdd(&pooled[(size_t)cur * 256 + gcol], s);
                    s = 0.f; cur = gg;
                }
                s += h2f(zs[r][swz(colL, r)]);
            }
            atomicAdd(&pooled[(size_t)cur * 256 + gcol], s);
        }
        __syncthreads();
    }
}

// ---------------- small f32 GEMM (GEMM3a, GEMM4) ----------------
enum { E_BIAS = 0, E_BNRELU = 1 };
template <int EMODE>
__global__ void __launch_bounds__(256)
gemm_k(const void* __restrict__ Av, const float* __restrict__ B,
       const float* __restrict__ bias,
       const float* __restrict__ g_, const float* __restrict__ b_,
       const float* __restrict__ m_, const float* __restrict__ v_,
       const float* __restrict__ scp,
       void* __restrict__ outv, int K, int Nc) {
    __shared__ float As[64][33];
    __shared__ float Bs[32][64];
    const int tid = threadIdx.x;
    const int row0 = blockIdx.x * 64;
    const int col0 = blockIdx.y * 64;
    float acc[4][4] = {};
    const int tx = tid & 15, ty = tid >> 4;
    for (int k0 = 0; k0 < K; k0 += 32) {
#pragma unroll
        for (int p = 0; p < 2; ++p) {
            int idx = p * 256 + tid;
            {
                int r = idx >> 3, c = (idx & 7) << 2;
                size_t aoff = (size_t)(row0 + r) * K + k0 + c;
                float4 va = *(const float4*)((const float*)Av + aoff);
                As[r][c + 0] = va.x; As[r][c + 1] = va.y;
                As[r][c + 2] = va.z; As[r][c + 3] = va.w;
            }
            {
                int kr = idx >> 4, cc = (idx & 15) << 2;
                *(float4*)&Bs[kr][cc] =
                    *(const float4*)(B + (size_t)(k0 + kr) * Nc + col0 + cc);
            }
        }
        __syncthreads();
#pragma unroll
        for (int k = 0; k < 32; ++k) {
            float4 bv = *(const float4*)&Bs[k][tx << 2];
            float a0 = As[ty * 4 + 0][k];
            float a1 = As[ty * 4 + 1][k];
            float a2 = As[ty * 4 + 2][k];
            float a3 = As[ty * 4 + 3][k];
            acc[0][0] += a0 * bv.x; acc[0][1] += a0 * bv.y; acc[0][2] += a0 * bv.z; acc[0][3] += a0 * bv.w;
            acc[1][0] += a1 * bv.x; acc[1][1] += a1 * bv.y; acc[1][2] += a1 * bv.z; acc[1][3] += a1 * bv.w;
            acc[2][0] += a2 * bv.x; acc[2][1] += a2 * bv.y; acc[2][2] += a2 * bv.z; acc[2][3] += a2 * bv.w;
            acc[3][0] += a3 * bv.x; acc[3][1] += a3 * bv.y; acc[3][2] += a3 * bv.z; acc[3][3] += a3 * bv.w;
        }
        __syncthreads();
    }
#pragma unroll
    for (int j = 0; j < 4; ++j) {
        int gr = row0 + ty * 4 + j;
        float vals[4];
#pragma unroll
        for (int lx = 0; lx < 4; ++lx) {
            int gc = col0 + (tx << 2) + lx;
            float val = acc[j][lx];
            if (EMODE == E_BIAS) {
                float v = val + bias[gc];
                if (scp) v *= scp[gc];
                vals[lx] = v;
            } else {
                float y = val + bias[gc];
                float s = g_[gc] * rsqrtf(v_[gc] + 1e-5f);
                y = (y - m_[gc]) * s + b_[gc];
                vals[lx] = fmaxf(y, 0.f);
            }
        }
        *(float4*)((float*)outv + (size_t)gr * Nc + col0 + (tx << 2)) =
            make_float4(vals[0], vals[1], vals[2], vals[3]);
    }
}

// ---------------- final head ----------------
__global__ void k_final(const float* __restrict__ vn, const float* __restrict__ pW1,
                        const float* __restrict__ pb1, const float* __restrict__ pW2,
                        const float* __restrict__ pb2, float* __restrict__ out) {
    int g = blockIdx.x;
    int j = threadIdx.x;
    __shared__ float vrow[HH];
    __shared__ float red[HH];
    vrow[j] = vn[(size_t)g * HH + j];
    __syncthreads();
    float acc = pb1[j];
    for (int k = 0; k < HH; ++k) acc = fmaf(vrow[k], pW1[k * HH + j], acc);
    red[j] = fmaxf(acc, 0.f) * pW2[j];
    __syncthreads();
    for (int s = 64; s > 0; s >>= 1) {
        if (j < s) red[j] += red[j + s];
        __syncthreads();
    }
    if (j == 0) out[g] = fminf(fmaxf(red[0] + pb2[0], 0.f), 50.f);
}

extern "C" void kernel_launch(void* const* d_in, const int* in_sizes, int n_in,
                              void* d_out, int out_size, void* d_ws, size_t ws_size,
                              hipStream_t stream) {
    const int*   x        = (const int*)  d_in[0];
    const int*   ei       = (const int*)  d_in[1];
    const int*   ea       = (const int*)  d_in[2];
    const int*   batch    = (const int*)  d_in[3];
    const float* atom_emb = (const float*)d_in[4];
    const float* vn_emb   = (const float*)d_in[5];
    const float* bond_emb = (const float*)d_in[6];
    const float* conv_eps = (const float*)d_in[7];
    const float* conv_W1  = (const float*)d_in[8];
    const float* conv_b1  = (const float*)d_in[9];
    const float* cbn_g    = (const float*)d_in[10];
    const float* cbn_b    = (const float*)d_in[11];
    const float* cbn_m    = (const float*)d_in[12];
    const float* cbn_v    = (const float*)d_in[13];
    const float* conv_W2  = (const float*)d_in[14];
    const float* conv_b2  = (const float*)d_in[15];
    const float* vn1_W    = (const float*)d_in[16];
    const float* vn1_b    = (const float*)d_in[17];
    const float* vn1_g    = (const float*)d_in[18];
    const float* vn1_be   = (const float*)d_in[19];
    const float* vn1_m    = (const float*)d_in[20];
    const float* vn1_v    = (const float*)d_in[21];
    const float* vn2_W    = (const float*)d_in[22];
    const float* vn2_b    = (const float*)d_in[23];
    const float* vn2_g    = (const float*)d_in[24];
    const float* vn2_be   = (const float*)d_in[25];
    const float* vn2_m    = (const float*)d_in[26];
    const float* vn2_v    = (const float*)d_in[27];
    const float* pW1      = (const float*)d_in[28];
    const float* pb1      = (const float*)d_in[29];
    const float* pW2      = (const float*)d_in[30];
    const float* pb2      = (const float*)d_in[31];

    // ---- workspace layout ----
    char* base = (char*)d_ws;
    ushort*   h16     = (ushort*)base;                                // NN*HH fp16
    ushort*   hb16    = h16 + (size_t)NN * HH;                        // NN*HH fp16
    unsigned* packed  = (unsigned*)(hb16 + (size_t)NN * HH);          // EE u32
    int*      rowptr  = (int*)(packed + EE);                          // NN+4
    int*      fill    = rowptr + NN + 4;                              // NN
    int*      sums    = fill + NN;                                    // 256
    ushort*   ct16a   = (ushort*)(sums + 256);                        // 4*512*128
    ushort*   W1ta    = ct16a + 4 * 512 * HH;                         // 4*32768
    ushort*   W2ta    = W1ta + 4 * 32768;
    ushort*   W3ta    = W2ta + 4 * 32768;
    float*    tabs    = (float*)(W3ta + 4 * 32768);                   // 4*1280
    float*    vn      = tabs + 4 * 1280;                              // GG*128
    float*    vnW     = vn + (size_t)GG * HH;                         // GG*256
    float*    pooled  = vnW + (size_t)GG * 256;                       // GG*256
    float*    out     = (float*)d_out;

    // ---- one-time setup ----
    k_zero<<<256, 256, 0, stream>>>((float*)fill);
    k_hist<<<EE / 256, 256, 0, stream>>>(ei, fill);
    k_scan1<<<256, 256, 0, stream>>>(fill, rowptr, sums);
    k_scan2<<<1, 256, 0, stream>>>(sums);
    k_scan3<<<256, 256, 0, stream>>>(rowptr, sums, fill);
    k_scatter<<<EE / 256, 256, 0, stream>>>(ei, ea, fill, packed);
    k_atom<<<NN * 32 / 256, 256, 0, stream>>>(x, atom_emb, h16);
    k_init_vn<<<GG * HH / 4 / 256, 256, 0, stream>>>(vn_emb, vn);
    k_setup_all<<<4 * 449, 256, 0, stream>>>(
        bond_emb, ct16a,
        conv_b1, cbn_g, cbn_b, cbn_m, cbn_v,
        vn1_g, vn1_be, vn1_m, vn1_v,
        tabs, conv_W1, W1ta, conv_W2, W2ta, vn1_W, W3ta);

    for (int i = 0; i < 4; ++i) {
        // GEMM4 (i>0): vn = relu(bn(pooled @ vn2_W + vn2_b))
        if (i > 0) {
            dim3 g4(GG / 64, 2);
            gemm_k<E_BNRELU><<<g4, 256, 0, stream>>>(
                pooled, vn2_W + (size_t)(i - 1) * 256 * HH, vn2_b + (i - 1) * HH,
                vn2_g + (i - 1) * HH, vn2_be + (i - 1) * HH,
                vn2_m + (i - 1) * HH, vn2_v + (i - 1) * HH,
                nullptr, vn, 256, HH);
        }
        // GEMM3a: vnW' = (vn @ vn1_W[:128] + vn1_b) * S3
        {
            dim3 g3(GG / 64, 4);
            gemm_k<E_BIAS><<<g3, 256, 0, stream>>>(
                vn, vn1_W + (size_t)i * 256 * 256, vn1_b + i * 256,
                nullptr, nullptr, nullptr, nullptr,
                tabs + (size_t)i * 1280 + 4 * 256, vnW, HH, 256);
        }
        // hb16 = h16 + vn[batch]/16, + zero pooled (fused tail)
        k_hb16<<<NN * 16 / 256 + GG * 256 / 4 / 256, 256, 0, stream>>>(
            h16, vn, batch, hb16, pooled);
        // mega-kernel v8
        k_conv<<<NN / 64, 256, 0, stream>>>(
            h16, hb16, rowptr, packed,
            ct16a + (size_t)i * 512 * HH,
            W1ta + (size_t)i * 32768, W2ta + (size_t)i * 32768, W3ta + (size_t)i * 32768,
            batch, vnW, conv_eps + i, tabs + (size_t)i * 1280,
            conv_b2 + i * HH, pooled);
    }
    // final GEMM4 -> vn, then head
    {
        dim3 g4(GG / 64, 2);
        gemm_k<E_BNRELU><<<g4, 256, 0, stream>>>(
            pooled, vn2_W + (size_t)3 * 256 * HH, vn2_b + 3 * HH,
            vn2_g + 3 * HH, vn2_be + 3 * HH, vn2_m + 3 * HH, vn2_v + 3 * HH,
            nullptr, vn, 256, HH);
    }
    k_final<<<GG, 128, 0, stream>>>(vn, pW1, pb1, pW2, pb2, out);
}

// Round 19
// 1454.166 us; speedup vs baseline: 1.0510x; 1.0510x over previous
//
#include <hip/hip_runtime.h>
#include <hip/hip_fp16.h>

#define NN 262144
#define EE 1048576
#define GG 8192
#define HH 128
#define FBc 3
#define VAc 64
#define VBc 8
#define FAc 9

typedef _Float16 f16;
typedef _Float16 f16x8 __attribute__((ext_vector_type(8)));
typedef float f32x4 __attribute__((ext_vector_type(4)));

__device__ __forceinline__ float h2f(ushort u) {
    __half h; *(ushort*)&h = u; return __half2float(h);
}
__device__ __forceinline__ ushort f2h(float f) {
    __half h = __float2half_rn(f); return *(ushort*)&h;
}
__device__ __forceinline__ int swz(int col, int row) {
    return (((col >> 3) ^ (row & 7)) << 3) | (col & 7);
}

// ---------------- zero fill ----------------
__global__ void k_zero(float* __restrict__ p) {
    size_t i = (size_t)(blockIdx.x * 256 + threadIdx.x) * 4;
    *(float4*)(p + i) = make_float4(0.f, 0.f, 0.f, 0.f);
}

// ---------------- atom encoder: h16 = (sum emb)/16 fp16 ----------------
__global__ void k_atom(const int* __restrict__ x, const float* __restrict__ emb,
                       ushort* __restrict__ h16) {
    int t = blockIdx.x * 256 + threadIdx.x;
    int n = t >> 5, c = (t & 31) << 2;
    if (n >= NN) return;
    float4 a = make_float4(0.f, 0.f, 0.f, 0.f);
#pragma unroll
    for (int f = 0; f < FAc; ++f) {
        int v = x[n * FAc + f];
        float4 e = *(const float4*)(emb + ((size_t)(f * VAc + v)) * HH + c);
        a.x += e.x; a.y += e.y; a.z += e.z; a.w += e.w;
    }
    ushort4 o;
    o.x = f2h(a.x * 0.0625f); o.y = f2h(a.y * 0.0625f);
    o.z = f2h(a.z * 0.0625f); o.w = f2h(a.w * 0.0625f);
    *(ushort4*)(h16 + (size_t)n * HH + c) = o;
}

// ---------------- vn init ----------------
__global__ void k_init_vn(const float* __restrict__ vn_emb, float* __restrict__ vn) {
    int t = blockIdx.x * 256 + threadIdx.x;
    int g = t >> 5, c = (t & 31) << 2;
    *(float4*)(vn + (size_t)g * HH + c) = *(const float4*)(vn_emb + c);
}

// ---------------- hb16 = h16 + vn[batch]/16, plus pooled zero (tail blocks) ----------------
__global__ void k_hb16(const ushort* __restrict__ h16, const float* __restrict__ vn,
                       const int* __restrict__ batch, ushort* __restrict__ hb16,
                       float* __restrict__ pooled) {
    int b = blockIdx.x;
    if (b >= NN * 16 / 256) {               // tail: zero pooled
        size_t i = (size_t)((b - NN * 16 / 256) * 256 + threadIdx.x) * 4;
        *(float4*)(pooled + i) = make_float4(0.f, 0.f, 0.f, 0.f);
        return;
    }
    int t = b * 256 + threadIdx.x;          // NN*16 threads
    int n = t >> 4, ch0 = (t & 15) * 8;
    int g = batch[n];
    f16x8 hv = *(const f16x8*)(h16 + (size_t)n * HH + ch0);
    const float* vp = vn + (size_t)g * HH + ch0;
    float4 v0 = *(const float4*)vp, v1 = *(const float4*)(vp + 4);
    float vv[8] = {v0.x, v0.y, v0.z, v0.w, v1.x, v1.y, v1.z, v1.w};
    f16x8 o;
#pragma unroll
    for (int j = 0; j < 8; ++j) o[j] = (f16)((float)hv[j] + vv[j] * 0.0625f);
    *(f16x8*)(hb16 + (size_t)n * HH + ch0) = o;
}

// ================= CSR build =================
__global__ void k_hist(const int* __restrict__ ei, int* __restrict__ deg) {
    int e = blockIdx.x * 256 + threadIdx.x;
    atomicAdd(&deg[ei[EE + e]], 1);
}
__global__ void k_scan1(const int* __restrict__ deg, int* __restrict__ rowptr,
                        int* __restrict__ sums) {
    __shared__ int s[256];
    int base = blockIdx.x * 1024 + threadIdx.x * 4;
    int4 d = *(const int4*)(deg + base);
    int t = d.x + d.y + d.z + d.w;
    s[threadIdx.x] = t;
    __syncthreads();
    for (int off = 1; off < 256; off <<= 1) {
        int v = (threadIdx.x >= off) ? s[threadIdx.x - off] : 0;
        __syncthreads();
        s[threadIdx.x] += v;
        __syncthreads();
    }
    int excl = s[threadIdx.x] - t;
    int4 o; o.x = excl; o.y = excl + d.x; o.z = o.y + d.y; o.w = o.z + d.z;
    *(int4*)(rowptr + base) = o;
    if (threadIdx.x == 255) sums[blockIdx.x] = s[255];
}
__global__ void k_scan2(int* __restrict__ sums) {
    __shared__ int s[256];
    int t = sums[threadIdx.x];
    s[threadIdx.x] = t;
    __syncthreads();
    for (int off = 1; off < 256; off <<= 1) {
        int v = (threadIdx.x >= off) ? s[threadIdx.x - off] : 0;
        __syncthreads();
        s[threadIdx.x] += v;
        __syncthreads();
    }
    sums[threadIdx.x] = s[threadIdx.x] - t;
}
__global__ void k_scan3(int* __restrict__ rowptr, const int* __restrict__ sums,
                        int* __restrict__ fill) {
    int base = blockIdx.x * 1024 + threadIdx.x * 4;
    int add = sums[blockIdx.x];
    int4 r = *(const int4*)(rowptr + base);
    r.x += add; r.y += add; r.z += add; r.w += add;
    *(int4*)(rowptr + base) = r;
    *(int4*)(fill + base) = r;
    if (blockIdx.x == 0 && threadIdx.x == 0) rowptr[NN] = EE;
}
__global__ void k_scatter(const int* __restrict__ ei, const int* __restrict__ ea,
                          int* __restrict__ fill, unsigned* __restrict__ packed) {
    int e = blockIdx.x * 256 + threadIdx.x;
    int dst = ei[EE + e];
    int pos = atomicAdd(&fill[dst], 1);
    unsigned cb = (unsigned)(ea[e * 3 + 0] + ea[e * 3 + 1] * 8 + ea[e * 3 + 2] * 64);
    packed[pos] = (unsigned)ei[e] | (cb << 18);
}

// ============ one-shot setup for ALL layers ============
__global__ void k_setup_all(
    const float* __restrict__ bond_emb, ushort* __restrict__ ct16_all,
    const float* __restrict__ conv_b1, const float* __restrict__ cbn_g,
    const float* __restrict__ cbn_b, const float* __restrict__ cbn_m,
    const float* __restrict__ cbn_v,
    const float* __restrict__ vn1_g, const float* __restrict__ vn1_be,
    const float* __restrict__ vn1_m, const float* __restrict__ vn1_v,
    float* __restrict__ tabs,                      // per layer 1280 floats: ZA ZB TA TB S3
    const float* __restrict__ conv_W1, ushort* __restrict__ W1t_all,
    const float* __restrict__ conv_W2, ushort* __restrict__ W2t_all,
    const float* __restrict__ vn1_W,  ushort* __restrict__ W3t_all) {
    int layer = blockIdx.x / 449;
    int t = (blockIdx.x % 449) * 256 + threadIdx.x;
    if (t < 16384) {                        // ct16: (sum bemb)/16
        const float* bemb = bond_emb + (size_t)layer * FBc * VBc * HH;
        int cb = t >> 5, c = (t & 31) << 2;
        int a0 = cb & 7, a1 = (cb >> 3) & 7, a2 = cb >> 6;
        float4 b0 = *(const float4*)(bemb + (size_t)(0 * VBc + a0) * HH + c);
        float4 b1v = *(const float4*)(bemb + (size_t)(1 * VBc + a1) * HH + c);
        float4 b2v = *(const float4*)(bemb + (size_t)(2 * VBc + a2) * HH + c);
        ushort4 o;
        o.x = f2h((b0.x + b1v.x + b2v.x) * 0.0625f);
        o.y = f2h((b0.y + b1v.y + b2v.y) * 0.0625f);
        o.z = f2h((b0.z + b1v.z + b2v.z) * 0.0625f);
        o.w = f2h((b0.w + b1v.w + b2v.w) * 0.0625f);
        *(ushort4*)(ct16_all + (size_t)layer * 512 * HH + (size_t)cb * HH + c) = o;
    } else if (t < 16640) {                 // BN tables
        int c = t - 16384;
        float* T = tabs + (size_t)layer * 1280;
        float s1 = cbn_g[layer * 256 + c] * rsqrtf(cbn_v[layer * 256 + c] + 1e-5f);
        T[0 * 256 + c] = s1;
        T[1 * 256 + c] = ((conv_b1[layer * 256 + c] - cbn_m[layer * 256 + c]) * s1
                          + cbn_b[layer * 256 + c]) * 0.0625f;
        float s3 = vn1_g[layer * 256 + c] * rsqrtf(vn1_v[layer * 256 + c] + 1e-5f);
        T[2 * 256 + c] = 16.f * s3;
        T[3 * 256 + c] = vn1_be[layer * 256 + c] - vn1_m[layer * 256 + c] * s3;
        T[4 * 256 + c] = s3;
    } else if (t < 49408) {                 // W1t [256][128]
        int o = t - 16640;
        int c = o >> 7, k = o & 127;
        W1t_all[(size_t)layer * 32768 + o] =
            f2h(conv_W1[(size_t)layer * 128 * 256 + (size_t)k * 256 + c]);
    } else if (t < 82176) {                 // W2t [128][256]
        int o = t - 49408;
        int c = o >> 8, k = o & 255;
        W2t_all[(size_t)layer * 32768 + o] =
            f2h(conv_W2[(size_t)layer * 256 * 128 + (size_t)k * 128 + c]);
    } else if (t < 114944) {                // W3t [256][128]
        int o = t - 82176;
        int c = o >> 7, k = o & 127;
        W3t_all[(size_t)layer * 32768 + o] =
            f2h(vn1_W[(size_t)layer * 256 * 256 + 128 * 256 + (size_t)k * 256 + c]);
    }
}

// ============== mega-kernel v7 (r17-proven): fused edge-gather + conv MLP + pool ==============
__global__ void __launch_bounds__(256, 3)
k_conv(ushort* __restrict__ h16, const ushort* __restrict__ hb16,
       const int* __restrict__ rowptr, const unsigned* __restrict__ packed,
       const ushort* __restrict__ ct16,
       const ushort* __restrict__ W1t, const ushort* __restrict__ W2t,
       const ushort* __restrict__ W3t,
       const int* __restrict__ batch, const float* __restrict__ vnW,
       const float* __restrict__ eps_ptr, const float* __restrict__ tabs,
       const float* __restrict__ b2,
       float* __restrict__ pooled) {
    __shared__ ushort zs[64][256];
    __shared__ ushort Wb[64][128];
    ushort(*Wb2)[256] = (ushort(*)[256]) & Wb[0][0];
    const int tid = threadIdx.x;
    const int r0 = blockIdx.x * 64;
    const int w = tid >> 6, l = tid & 63, lr = l & 15, lg = l >> 4, lr7 = lr & 7;
    const float eps1 = 1.f + eps_ptr[0];
    const int myrow = w * 16 + lr;
    const int growA = r0 + myrow;
    const float* ZA = tabs;
    const float* ZB = tabs + 256;
    const float* TA = tabs + 512;
    const float* TB = tabs + 768;
    int rl[4], ggs[4];
#pragma unroll
    for (int reg = 0; reg < 4; ++reg) {
        rl[reg] = w * 16 + lg * 4 + reg;
        ggs[reg] = batch[r0 + rl[reg]];
    }

    // ---- fused edge gather: agg/16 -> zs cols 0-127 (sequential 4-edge unroll) ----
    {
        int grp = tid >> 4, ln = tid & 15;
        int ch0 = ln * 8;
        for (int rr = 0; rr < 4; ++rr) {
            int row = grp * 4 + rr;
            int beg = rowptr[r0 + row], end = rowptr[r0 + row + 1];
            float ac[8] = {0.f, 0.f, 0.f, 0.f, 0.f, 0.f, 0.f, 0.f};
            int e = beg;
            for (; e + 3 < end; e += 4) {
                unsigned p0 = packed[e], p1 = packed[e + 1];
                unsigned p2 = packed[e + 2], p3 = packed[e + 3];
                f16x8 h0 = *(const f16x8*)(hb16 + (size_t)(p0 & 0x3FFFF) * HH + ch0);
                f16x8 h1 = *(const f16x8*)(hb16 + (size_t)(p1 & 0x3FFFF) * HH + ch0);
                f16x8 h2 = *(const f16x8*)(hb16 + (size_t)(p2 & 0x3FFFF) * HH + ch0);
                f16x8 h3 = *(const f16x8*)(hb16 + (size_t)(p3 & 0x3FFFF) * HH + ch0);
                f16x8 t0 = *(const f16x8*)(ct16 + (size_t)(p0 >> 18) * HH + ch0);
                f16x8 t1 = *(const f16x8*)(ct16 + (size_t)(p1 >> 18) * HH + ch0);
                f16x8 t2 = *(const f16x8*)(ct16 + (size_t)(p2 >> 18) * HH + ch0);
                f16x8 t3 = *(const f16x8*)(ct16 + (size_t)(p3 >> 18) * HH + ch0);
#pragma unroll
                for (int j = 0; j < 8; ++j) {
                    ac[j] += fmaxf((float)h0[j] + (float)t0[j], 0.f)
                           + fmaxf((float)h1[j] + (float)t1[j], 0.f)
                           + fmaxf((float)h2[j] + (float)t2[j], 0.f)
                           + fmaxf((float)h3[j] + (float)t3[j], 0.f);
                }
            }
            for (; e < end; ++e) {
                unsigned p = packed[e];
                f16x8 hv = *(const f16x8*)(hb16 + (size_t)(p & 0x3FFFF) * HH + ch0);
                f16x8 ct = *(const f16x8*)(ct16 + (size_t)(p >> 18) * HH + ch0);
#pragma unroll
                for (int j = 0; j < 8; ++j)
                    ac[j] += fmaxf((float)hv[j] + (float)ct[j], 0.f);
            }
            f16x8 o;
#pragma unroll
            for (int j = 0; j < 8; ++j) o[j] = (f16)ac[j];
            *(f16x8*)&zs[row][((ch0 >> 3) ^ (row & 7)) << 3] = o;
        }
    }
    __syncthreads();

    // ---- A fragments: A/16 = eps1*hb16 + agg16(zs) ----
    f16x8 af[4];
#pragma unroll
    for (int k0 = 0; k0 < 4; ++k0) {
        int ko = k0 * 32 + lg * 8;
        f16x8 hb = *(const f16x8*)(hb16 + (size_t)growA * HH + ko);
        f16x8 ag = *(const f16x8*)&zs[myrow][((ko >> 3) ^ (myrow & 7)) << 3];
#pragma unroll
        for (int j = 0; j < 8; ++j)
            af[k0][j] = (f16)(eps1 * (float)hb[j] + (float)ag[j]);
    }

    // ---- phase A ----
    for (int qt = 0; qt < 4; ++qt) {
        __syncthreads();
        {
            int c = tid >> 2, q = tid & 3, c7 = c & 7;
            const ushort* s = W1t + (size_t)(qt * 64 + c) * 128 + q * 32;
#pragma unroll
            for (int j4 = 0; j4 < 4; ++j4)
                *(f16x8*)&Wb[c][((q * 4 + j4) ^ c7) << 3] = *(const f16x8*)(s + j4 * 8);
        }
        __syncthreads();
        f32x4 acc[4] = {};
        __builtin_amdgcn_s_setprio(1);
#pragma unroll
        for (int k0 = 0; k0 < 4; ++k0) {
            int sb = ((k0 * 4 + lg) ^ lr7) << 3;
#pragma unroll
            for (int fc = 0; fc < 4; ++fc) {
                f16x8 bf = *(const f16x8*)&Wb[fc * 16 + lr][sb];
                acc[fc] = __builtin_amdgcn_mfma_f32_16x16x32_f16(af[k0], bf, acc[fc], 0, 0, 0);
            }
        }
        __builtin_amdgcn_s_setprio(0);
#pragma unroll
        for (int fc = 0; fc < 4; ++fc) {
            int col = qt * 64 + fc * 16 + lr;
            float za = ZA[col], zb = ZB[col];
#pragma unroll
            for (int reg = 0; reg < 4; ++reg) {
                float zv = fmaxf(acc[fc][reg] * za + zb, 0.f);
                zs[rl[reg]][swz(col, rl[reg])] = f2h(zv);
            }
        }
    }

    // ---- phase B ----
    f32x4 acc2[8] = {};
    for (int st = 0; st < 4; ++st) {
        __syncthreads();
        {
            int c = tid >> 3, q = tid & 7, c7 = c & 7;
            const ushort* s = W2t + (size_t)(st * 32 + c) * 256 + q * 32;
#pragma unroll
            for (int j4 = 0; j4 < 4; ++j4)
                *(f16x8*)&Wb2[c][((q * 4 + j4) ^ c7) << 3] = *(const f16x8*)(s + j4 * 8);
        }
        __syncthreads();
        __builtin_amdgcn_s_setprio(1);
#pragma unroll
        for (int k0 = 0; k0 < 8; ++k0) {
            int sb = ((k0 * 4 + lg) ^ lr7) << 3;
            f16x8 az = *(const f16x8*)&zs[myrow][sb];
#pragma unroll
            for (int fc = 0; fc < 2; ++fc) {
                f16x8 bf = *(const f16x8*)&Wb2[fc * 16 + lr][sb];
                acc2[st * 2 + fc] =
                    __builtin_amdgcn_mfma_f32_16x16x32_f16(az, bf, acc2[st * 2 + fc], 0, 0, 0);
            }
        }
        __builtin_amdgcn_s_setprio(0);
    }
    __syncthreads();
#pragma unroll
    for (int st = 0; st < 4; ++st) {
#pragma unroll
        for (int fc = 0; fc < 2; ++fc) {
            int col = st * 32 + fc * 16 + lr;
            float bb = b2[col];
#pragma unroll
            for (int reg = 0; reg < 4; ++reg) {
                float hv = acc2[st * 2 + fc][reg] * 16.f + bb;
                zs[rl[reg]][swz(col, rl[reg])] = f2h(hv * 0.0625f);
            }
        }
    }
    {
        int row = tid >> 2, q = tid & 3, r7 = row & 7;
#pragma unroll
        for (int j4 = 0; j4 < 4; ++j4) {
            f16x8 v = *(const f16x8*)&zs[row][((q * 4 + j4) ^ r7) << 3];
            *(f16x8*)(h16 + (size_t)(r0 + row) * HH + q * 32 + j4 * 8) = v;
        }
    }

    // ---- phase C + pool ----
    for (int pr = 0; pr < 2; ++pr) {
#pragma unroll
        for (int sub = 0; sub < 2; ++sub) {
            int qt = pr * 2 + sub;
            __syncthreads();
            {
                int c = tid >> 2, q = tid & 3, c7 = c & 7;
                const ushort* s = W3t + (size_t)(qt * 64 + c) * 128 + q * 32;
#pragma unroll
                for (int j4 = 0; j4 < 4; ++j4)
                    *(f16x8*)&Wb[c][((q * 4 + j4) ^ c7) << 3] = *(const f16x8*)(s + j4 * 8);
            }
            __syncthreads();
            f32x4 acc3[4] = {};
            __builtin_amdgcn_s_setprio(1);
#pragma unroll
            for (int k0 = 0; k0 < 4; ++k0) {
                int sb = ((k0 * 4 + lg) ^ lr7) << 3;
                f16x8 ah = *(const f16x8*)&zs[myrow][sb];
#pragma unroll
                for (int fc = 0; fc < 4; ++fc) {
                    f16x8 bf = *(const f16x8*)&Wb[fc * 16 + lr][sb];
                    acc3[fc] = __builtin_amdgcn_mfma_f32_16x16x32_f16(ah, bf, acc3[fc], 0, 0, 0);
                }
            }
            __builtin_amdgcn_s_setprio(0);
#pragma unroll
            for (int fc = 0; fc < 4; ++fc) {
                int colg = qt * 64 + fc * 16 + lr;
                int colL = 128 + sub * 64 + fc * 16 + lr;
                float ta = TA[colg], tb = TB[colg];
#pragma unroll
                for (int reg = 0; reg < 4; ++reg) {
                    float tv = fmaxf(acc3[fc][reg] * ta + vnW[(size_t)ggs[reg] * 256 + colg] + tb, 0.f);
                    zs[rl[reg]][swz(colL, rl[reg])] = f2h(tv);
                }
            }
        }
        __syncthreads();
        {
            int c = tid & 127, half = tid >> 7;
            int gcol = pr * 128 + c;
            int colL = 128 + c;
            float s = 0.f;
            int cur = batch[r0 + half * 32];
            for (int r = half * 32; r < half * 32 + 32; ++r) {
                int gg = batch[r0 + r];
                if (gg != cur) {
                    atomicAdd(&pooled[(size_t)cur * 256 + gcol], s);
                    s = 0.f; cur = gg;
                }
                s += h2f(zs[r][swz(colL, r)]);
            }
            atomicAdd(&pooled[(size_t)cur * 256 + gcol], s);
        }
        __syncthreads();
    }
}

// ---------------- small f32 GEMM (GEMM3a, GEMM4) ----------------
enum { E_BIAS = 0, E_BNRELU = 1 };
template <int EMODE>
__global__ void __launch_bounds__(256)
gemm_k(const void* __restrict__ Av, const float* __restrict__ B,
       const float* __restrict__ bias,
       const float* __restrict__ g_, const float* __restrict__ b_,
       const float* __restrict__ m_, const float* __restrict__ v_,
       const float* __restrict__ scp,
       void* __restrict__ outv, int K, int Nc) {
    __shared__ float As[64][33];
    __shared__ float Bs[32][64];
    const int tid = threadIdx.x;
    const int row0 = blockIdx.x * 64;
    const int col0 = blockIdx.y * 64;
    float acc[4][4] = {};
    const int tx = tid & 15, ty = tid >> 4;
    for (int k0 = 0; k0 < K; k0 += 32) {
#pragma unroll
        for (int p = 0; p < 2; ++p) {
            int idx = p * 256 + tid;
            {
                int r = idx >> 3, c = (idx & 7) << 2;
                size_t aoff = (size_t)(row0 + r) * K + k0 + c;
                float4 va = *(const float4*)((const float*)Av + aoff);
                As[r][c + 0] = va.x; As[r][c + 1] = va.y;
                As[r][c + 2] = va.z; As[r][c + 3] = va.w;
            }
            {
                int kr = idx >> 4, cc = (idx & 15) << 2;
                *(float4*)&Bs[kr][cc] =
                    *(const float4*)(B + (size_t)(k0 + kr) * Nc + col0 + cc);
            }
        }
        __syncthreads();
#pragma unroll
        for (int k = 0; k < 32; ++k) {
            float4 bv = *(const float4*)&Bs[k][tx << 2];
            float a0 = As[ty * 4 + 0][k];
            float a1 = As[ty * 4 + 1][k];
            float a2 = As[ty * 4 + 2][k];
            float a3 = As[ty * 4 + 3][k];
            acc[0][0] += a0 * bv.x; acc[0][1] += a0 * bv.y; acc[0][2] += a0 * bv.z; acc[0][3] += a0 * bv.w;
            acc[1][0] += a1 * bv.x; acc[1][1] += a1 * bv.y; acc[1][2] += a1 * bv.z; acc[1][3] += a1 * bv.w;
            acc[2][0] += a2 * bv.x; acc[2][1] += a2 * bv.y; acc[2][2] += a2 * bv.z; acc[2][3] += a2 * bv.w;
            acc[3][0] += a3 * bv.x; acc[3][1] += a3 * bv.y; acc[3][2] += a3 * bv.z; acc[3][3] += a3 * bv.w;
        }
        __syncthreads();
    }
#pragma unroll
    for (int j = 0; j < 4; ++j) {
        int gr = row0 + ty * 4 + j;
        float vals[4];
#pragma unroll
        for (int lx = 0; lx < 4; ++lx) {
            int gc = col0 + (tx << 2) + lx;
            float val = acc[j][lx];
            if (EMODE == E_BIAS) {
                float v = val + bias[gc];
                if (scp) v *= scp[gc];
                vals[lx] = v;
            } else {
                float y = val + bias[gc];
                float s = g_[gc] * rsqrtf(v_[gc] + 1e-5f);
                y = (y - m_[gc]) * s + b_[gc];
                vals[lx] = fmaxf(y, 0.f);
            }
        }
        *(float4*)((float*)outv + (size_t)gr * Nc + col0 + (tx << 2)) =
            make_float4(vals[0], vals[1], vals[2], vals[3]);
    }
}

// ---------------- final head ----------------
__global__ void k_final(const float* __restrict__ vn, const float* __restrict__ pW1,
                        const float* __restrict__ pb1, const float* __restrict__ pW2,
                        const float* __restrict__ pb2, float* __restrict__ out) {
    int g = blockIdx.x;
    int j = threadIdx.x;
    __shared__ float vrow[HH];
    __shared__ float red[HH];
    vrow[j] = vn[(size_t)g * HH + j];
    __syncthreads();
    float acc = pb1[j];
    for (int k = 0; k < HH; ++k) acc = fmaf(vrow[k], pW1[k * HH + j], acc);
    red[j] = fmaxf(acc, 0.f) * pW2[j];
    __syncthreads();
    for (int s = 64; s > 0; s >>= 1) {
        if (j < s) red[j] += red[j + s];
        __syncthreads();
    }
    if (j == 0) out[g] = fminf(fmaxf(red[0] + pb2[0], 0.f), 50.f);
}

extern "C" void kernel_launch(void* const* d_in, const int* in_sizes, int n_in,
                              void* d_out, int out_size, void* d_ws, size_t ws_size,
                              hipStream_t stream) {
    const int*   x        = (const int*)  d_in[0];
    const int*   ei       = (const int*)  d_in[1];
    const int*   ea       = (const int*)  d_in[2];
    const int*   batch    = (const int*)  d_in[3];
    const float* atom_emb = (const float*)d_in[4];
    const float* vn_emb   = (const float*)d_in[5];
    const float* bond_emb = (const float*)d_in[6];
    const float* conv_eps = (const float*)d_in[7];
    const float* conv_W1  = (const float*)d_in[8];
    const float* conv_b1  = (const float*)d_in[9];
    const float* cbn_g    = (const float*)d_in[10];
    const float* cbn_b    = (const float*)d_in[11];
    const float* cbn_m    = (const float*)d_in[12];
    const float* cbn_v    = (const float*)d_in[13];
    const float* conv_W2  = (const float*)d_in[14];
    const float* conv_b2  = (const float*)d_in[15];
    const float* vn1_W    = (const float*)d_in[16];
    const float* vn1_b    = (const float*)d_in[17];
    const float* vn1_g    = (const float*)d_in[18];
    const float* vn1_be   = (const float*)d_in[19];
    const float* vn1_m    = (const float*)d_in[20];
    const float* vn1_v    = (const float*)d_in[21];
    const float* vn2_W    = (const float*)d_in[22];
    const float* vn2_b    = (const float*)d_in[23];
    const float* vn2_g    = (const float*)d_in[24];
    const float* vn2_be   = (const float*)d_in[25];
    const float* vn2_m    = (const float*)d_in[26];
    const float* vn2_v    = (const float*)d_in[27];
    const float* pW1      = (const float*)d_in[28];
    const float* pb1      = (const float*)d_in[29];
    const float* pW2      = (const float*)d_in[30];
    const float* pb2      = (const float*)d_in[31];

    // ---- workspace layout ----
    char* base = (char*)d_ws;
    ushort*   h16     = (ushort*)base;                                // NN*HH fp16
    ushort*   hb16    = h16 + (size_t)NN * HH;                        // NN*HH fp16
    unsigned* packed  = (unsigned*)(hb16 + (size_t)NN * HH);          // EE u32
    int*      rowptr  = (int*)(packed + EE);                          // NN+4
    int*      fill    = rowptr + NN + 4;                              // NN
    int*      sums    = fill + NN;                                    // 256
    ushort*   ct16a   = (ushort*)(sums + 256);                        // 4*512*128
    ushort*   W1ta    = ct16a + 4 * 512 * HH;                         // 4*32768
    ushort*   W2ta    = W1ta + 4 * 32768;
    ushort*   W3ta    = W2ta + 4 * 32768;
    float*    tabs    = (float*)(W3ta + 4 * 32768);                   // 4*1280
    float*    vn      = tabs + 4 * 1280;                              // GG*128
    float*    vnW     = vn + (size_t)GG * HH;                         // GG*256
    float*    pooled  = vnW + (size_t)GG * 256;                       // GG*256
    float*    out     = (float*)d_out;

    // ---- one-time setup ----
    k_zero<<<256, 256, 0, stream>>>((float*)fill);
    k_hist<<<EE / 256, 256, 0, stream>>>(ei, fill);
    k_scan1<<<256, 256, 0, stream>>>(fill, rowptr, sums);
    k_scan2<<<1, 256, 0, stream>>>(sums);
    k_scan3<<<256, 256, 0, stream>>>(rowptr, sums, fill);
    k_scatter<<<EE / 256, 256, 0, stream>>>(ei, ea, fill, packed);
    k_atom<<<NN * 32 / 256, 256, 0, stream>>>(x, atom_emb, h16);
    k_init_vn<<<GG * HH / 4 / 256, 256, 0, stream>>>(vn_emb, vn);
    k_setup_all<<<4 * 449, 256, 0, stream>>>(
        bond_emb, ct16a,
        conv_b1, cbn_g, cbn_b, cbn_m, cbn_v,
        vn1_g, vn1_be, vn1_m, vn1_v,
        tabs, conv_W1, W1ta, conv_W2, W2ta, vn1_W, W3ta);

    for (int i = 0; i < 4; ++i) {
        // GEMM4 (i>0): vn = relu(bn(pooled @ vn2_W + vn2_b))
        if (i > 0) {
            dim3 g4(GG / 64, 2);
            gemm_k<E_BNRELU><<<g4, 256, 0, stream>>>(
                pooled, vn2_W + (size_t)(i - 1) * 256 * HH, vn2_b + (i - 1) * HH,
                vn2_g + (i - 1) * HH, vn2_be + (i - 1) * HH,
                vn2_m + (i - 1) * HH, vn2_v + (i - 1) * HH,
                nullptr, vn, 256, HH);
        }
        // GEMM3a: vnW' = (vn @ vn1_W[:128] + vn1_b) * S3
        {
            dim3 g3(GG / 64, 4);
            gemm_k<E_BIAS><<<g3, 256, 0, stream>>>(
                vn, vn1_W + (size_t)i * 256 * 256, vn1_b + i * 256,
                nullptr, nullptr, nullptr, nullptr,
                tabs + (size_t)i * 1280 + 4 * 256, vnW, HH, 256);
        }
        // hb16 = h16 + vn[batch]/16, + zero pooled (fused tail)
        k_hb16<<<NN * 16 / 256 + GG * 256 / 4 / 256, 256, 0, stream>>>(
            h16, vn, batch, hb16, pooled);
        // mega-kernel v7
        k_conv<<<NN / 64, 256, 0, stream>>>(
            h16, hb16, rowptr, packed,
            ct16a + (size_t)i * 512 * HH,
            W1ta + (size_t)i * 32768, W2ta + (size_t)i * 32768, W3ta + (size_t)i * 32768,
            batch, vnW, conv_eps + i, tabs + (size_t)i * 1280,
            conv_b2 + i * HH, pooled);
    }
    // final GEMM4 -> vn, then head
    {
        dim3 g4(GG / 64, 2);
        gemm_k<E_BNRELU><<<g4, 256, 0, stream>>>(
            pooled, vn2_W + (size_t)3 * 256 * HH, vn2_b + 3 * HH,
            vn2_g + 3 * HH, vn2_be + 3 * HH, vn2_m + 3 * HH, vn2_v + 3 * HH,
            nullptr, vn, 256, HH);
    }
    k_final<<<GG, 128, 0, stream>>>(vn, pW1, pb1, pW2, pb2, out);
}